// Round 1
// baseline (840.012 us; speedup 1.0000x reference)
//
#include <hip/hip_runtime.h>
#include <stdint.h>

#define NG   64
#define NPG  4096
#define HD   256
#define NC0  256
#define NC1  64

typedef __attribute__((ext_vector_type(8))) short bfx8;   // 8 bf16 (4 VGPRs)
typedef __attribute__((ext_vector_type(4))) float fx4;    // MFMA acc

__device__ __forceinline__ unsigned short f2bf(float f) {
  union { float f; unsigned int u; } v; v.f = f;
  return (unsigned short)((v.u + 0x7FFFu + ((v.u >> 16) & 1u)) >> 16);  // RNE
}
__device__ __forceinline__ unsigned int pack2(float a, float b) {
  return (unsigned int)f2bf(a) | ((unsigned int)f2bf(b) << 16);
}

// ---------------- W0 -> W0T bf16 [c][h] ----------------
__global__ __launch_bounds__(256) void k_w0t(const float* __restrict__ W0,
                                             unsigned short* __restrict__ W0T) {
  int idx = blockIdx.x * 256 + threadIdx.x;   // idx = c*256 + h
  int c = idx >> 8, h = idx & 255;
  W0T[idx] = f2bf(W0[h * 256 + c]);
}

// ---------------- x (fp32 [node][h]) -> xT (bf16 [g][h][node]) ----------------
__global__ __launch_bounds__(256) void k_xt(const float* __restrict__ x,
                                            unsigned short* __restrict__ xT, int g0) {
  __shared__ unsigned short tile[64 * 256];   // [node][h]
  int gl = blockIdx.x >> 6, nt = blockIdx.x & 63;   // 64-node tile
  int t = threadIdx.x;                               // t = h
  const float* xp = x + ((size_t)(g0 + gl) * NPG + (size_t)nt * 64) * HD + t;
  for (int r = 0; r < 64; ++r)
    tile[r * 256 + t] = f2bf(xp[(size_t)r * 256]);
  __syncthreads();
  fx4 buf[8];
  unsigned int* bu = (unsigned int*)buf;
  #pragma unroll
  for (int n = 0; n < 64; n += 2)
    bu[n >> 1] = (unsigned int)tile[n * 256 + t] |
                 ((unsigned int)tile[(n + 1) * 256 + t] << 16);
  fx4* dst = (fx4*)(xT + ((size_t)gl * HD + t) * NPG + (size_t)nt * 64);
  #pragma unroll
  for (int i = 0; i < 8; ++i) dst[i] = buf[i];
}

// ---------------- K1: logits = x@W0 + b0, softmax rows, write A0T bf16 ----------------
// block: 512 thr (8 waves), tile 128 nodes x 256 clusters, K=256 (BK=64)
// wave grid 2(m) x 4(n): each wave 64x64 -> acc[4][4] fx4
#define K1PAD 72
__global__ __launch_bounds__(512, 1) void k_assign0(
    const float* __restrict__ x, const unsigned short* __restrict__ W0T,
    const float* __restrict__ b0, unsigned short* __restrict__ A0T, int g0) {
  __shared__ char smem[(128 + 256) * K1PAD * 2];   // 55296 B: xs[128][72] + wb[256][72]
  __shared__ float red[128 * 4];
  unsigned short* xs = (unsigned short*)smem;
  unsigned short* wb = (unsigned short*)(smem + 128 * K1PAD * 2);
  unsigned short* at = (unsigned short*)smem;      // epilogue alias: [128 c][136 n]

  int gl = blockIdx.x >> 5, nt = blockIdx.x & 31;
  int tid = threadIdx.x;
  int wave = tid >> 6, lane = tid & 63;
  int wm = wave >> 2, wn = wave & 3;
  int l15 = lane & 15, q = lane >> 4;

  fx4 acc[4][4];
  #pragma unroll
  for (int i = 0; i < 4; ++i)
    #pragma unroll
    for (int j = 0; j < 4; ++j) acc[i][j] = fx4{0.f, 0.f, 0.f, 0.f};

  const float* xbase = x + ((size_t)(g0 + gl) * NPG + (size_t)nt * 128) * HD;
  int snode = tid >> 2, sseg = (tid & 3) * 16;   // xs staging: 128 rows x 4 segs of 16
  int sc = tid >> 1, sseg2 = (tid & 1) * 32;     // wb staging: 256 rows x 2 segs of 32

  for (int kc = 0; kc < 4; ++kc) {
    int k0 = kc * 64;
    {   // x fp32 -> bf16 -> xs
      const float4* src = (const float4*)(xbase + (size_t)snode * HD + k0 + sseg);
      float4 v0 = src[0], v1 = src[1], v2 = src[2], v3 = src[3];
      float4 pv[2];
      unsigned int* pu = (unsigned int*)pv;
      pu[0] = pack2(v0.x, v0.y); pu[1] = pack2(v0.z, v0.w);
      pu[2] = pack2(v1.x, v1.y); pu[3] = pack2(v1.z, v1.w);
      pu[4] = pack2(v2.x, v2.y); pu[5] = pack2(v2.z, v2.w);
      pu[6] = pack2(v3.x, v3.y); pu[7] = pack2(v3.z, v3.w);
      float4* d = (float4*)(xs + snode * K1PAD + sseg);
      d[0] = pv[0]; d[1] = pv[1];
    }
    {   // W0T bf16 -> wb
      const float4* src = (const float4*)(W0T + sc * HD + k0 + sseg2);
      float4* d = (float4*)(wb + sc * K1PAD + sseg2);
      d[0] = src[0]; d[1] = src[1]; d[2] = src[2]; d[3] = src[3];
    }
    __syncthreads();
    #pragma unroll
    for (int ks = 0; ks < 2; ++ks) {
      int kk = ks * 32 + q * 8;
      bfx8 af[4];
      #pragma unroll
      for (int mi = 0; mi < 4; ++mi)
        af[mi] = *(const bfx8*)(xs + (wm * 64 + mi * 16 + l15) * K1PAD + kk);
      #pragma unroll
      for (int ni = 0; ni < 4; ++ni) {
        bfx8 bv = *(const bfx8*)(wb + (wn * 64 + ni * 16 + l15) * K1PAD + kk);
        #pragma unroll
        for (int mi = 0; mi < 4; ++mi)
          acc[mi][ni] = __builtin_amdgcn_mfma_f32_16x16x32_bf16(af[mi], bv, acc[mi][ni], 0, 0, 0);
      }
    }
    __syncthreads();
  }

  // ---- epilogue: bias + softmax over 256 clusters per node-row ----
  float bv[4];
  #pragma unroll
  for (int ni = 0; ni < 4; ++ni) bv[ni] = b0[wn * 64 + ni * 16 + l15];
  #pragma unroll
  for (int mi = 0; mi < 4; ++mi)
    #pragma unroll
    for (int ni = 0; ni < 4; ++ni)
      #pragma unroll
      for (int r = 0; r < 4; ++r) acc[mi][ni][r] += bv[ni];

  float mrow[4][4];
  #pragma unroll
  for (int mi = 0; mi < 4; ++mi)
    #pragma unroll
    for (int r = 0; r < 4; ++r) {
      float m = fmaxf(fmaxf(acc[mi][0][r], acc[mi][1][r]), fmaxf(acc[mi][2][r], acc[mi][3][r]));
      #pragma unroll
      for (int off = 1; off < 16; off <<= 1) m = fmaxf(m, __shfl_xor(m, off));
      mrow[mi][r] = m;
    }
  if (l15 == 0) {
    #pragma unroll
    for (int mi = 0; mi < 4; ++mi)
      #pragma unroll
      for (int r = 0; r < 4; ++r)
        red[(wm * 64 + mi * 16 + q * 4 + r) * 4 + wn] = mrow[mi][r];
  }
  __syncthreads();
  #pragma unroll
  for (int mi = 0; mi < 4; ++mi)
    #pragma unroll
    for (int r = 0; r < 4; ++r) {
      float4 rv = *(const float4*)&red[(wm * 64 + mi * 16 + q * 4 + r) * 4];
      mrow[mi][r] = fmaxf(fmaxf(rv.x, rv.y), fmaxf(rv.z, rv.w));
    }
  __syncthreads();
  float srow[4][4];
  #pragma unroll
  for (int mi = 0; mi < 4; ++mi)
    #pragma unroll
    for (int r = 0; r < 4; ++r) {
      float s = 0.f;
      #pragma unroll
      for (int ni = 0; ni < 4; ++ni) {
        float e = __expf(acc[mi][ni][r] - mrow[mi][r]);
        acc[mi][ni][r] = e; s += e;
      }
      #pragma unroll
      for (int off = 1; off < 16; off <<= 1) s += __shfl_xor(s, off);
      srow[mi][r] = s;
    }
  if (l15 == 0) {
    #pragma unroll
    for (int mi = 0; mi < 4; ++mi)
      #pragma unroll
      for (int r = 0; r < 4; ++r)
        red[(wm * 64 + mi * 16 + q * 4 + r) * 4 + wn] = srow[mi][r];
  }
  __syncthreads();
  #pragma unroll
  for (int mi = 0; mi < 4; ++mi)
    #pragma unroll
    for (int r = 0; r < 4; ++r) {
      float4 rv = *(const float4*)&red[(wm * 64 + mi * 16 + q * 4 + r) * 4];
      float inv = 1.f / (rv.x + rv.y + rv.z + rv.w);
      #pragma unroll
      for (int ni = 0; ni < 4; ++ni) acc[mi][ni][r] *= inv;
    }
  __syncthreads();   // done with xs/wb; reuse as 'at'

  // ---- transposed store: A0T[gl][c][node], two 128-cluster phases via LDS ----
  unsigned short* A0Tg = A0T + (size_t)gl * NC0 * NPG + (size_t)nt * 128;
  #pragma unroll
  for (int p = 0; p < 2; ++p) {
    if ((wn >> 1) == p) {
      int cb = (wn & 1) * 64;
      #pragma unroll
      for (int mi = 0; mi < 4; ++mi) {
        int ncol = wm * 64 + mi * 16 + q * 4;
        #pragma unroll
        for (int ni = 0; ni < 4; ++ni) {
          int cl = cb + ni * 16 + l15;
          uint2 w;
          w.x = pack2(acc[mi][ni][0], acc[mi][ni][1]);
          w.y = pack2(acc[mi][ni][2], acc[mi][ni][3]);
          *(uint2*)(at + cl * 136 + ncol) = w;
        }
      }
    }
    __syncthreads();
    {
      int row = tid >> 2, seg = (tid & 3) * 32;
      const float4* s4 = (const float4*)(at + row * 136 + seg);
      float4 a = s4[0], b = s4[1], c = s4[2], d = s4[3];
      float4* d4 = (float4*)(A0Tg + (size_t)(p * 128 + row) * NPG + seg);
      d4[0] = a; d4[1] = b; d4[2] = c; d4[3] = d;
    }
    __syncthreads();
  }
}

// ---------------- K2: f0[g][c][h] += A0T[g][c][:] . xT[g][h][:]  (split-K, atomics) ----------------
#define K2PAD 72
__global__ __launch_bounds__(256, 2) void k_pool0(
    const unsigned short* __restrict__ A0T, const unsigned short* __restrict__ xT,
    float* __restrict__ f0, int g0, int kper, int ksplit) {
  __shared__ unsigned short a_s[128 * K2PAD];
  __shared__ unsigned short b_s[128 * K2PAD];
  int bid = blockIdx.x;
  int gl = bid / (4 * ksplit);
  int rem = bid - gl * 4 * ksplit;
  int mt = rem / (2 * ksplit);
  int rem2 = rem - mt * 2 * ksplit;
  int nt = rem2 / ksplit;
  int kidx = rem2 - nt * ksplit;

  int tid = threadIdx.x;
  int wave = tid >> 6, lane = tid & 63;
  int wm = wave >> 1, wn = wave & 1;
  int l15 = lane & 15, q = lane >> 4;

  const unsigned short* abase = A0T + ((size_t)gl * NC0 + (size_t)mt * 128) * NPG + (size_t)kidx * kper;
  const unsigned short* bbase = xT + ((size_t)gl * HD + (size_t)nt * 128) * NPG + (size_t)kidx * kper;

  fx4 acc[4][4];
  #pragma unroll
  for (int i = 0; i < 4; ++i)
    #pragma unroll
    for (int j = 0; j < 4; ++j) acc[i][j] = fx4{0.f, 0.f, 0.f, 0.f};

  int srow = tid >> 1, sseg = (tid & 1) * 32;
  for (int k0 = 0; k0 < kper; k0 += 64) {
    {
      const float4* sa = (const float4*)(abase + (size_t)srow * NPG + k0 + sseg);
      float4* da = (float4*)(a_s + srow * K2PAD + sseg);
      da[0] = sa[0]; da[1] = sa[1]; da[2] = sa[2]; da[3] = sa[3];
      const float4* sb = (const float4*)(bbase + (size_t)srow * NPG + k0 + sseg);
      float4* db = (float4*)(b_s + srow * K2PAD + sseg);
      db[0] = sb[0]; db[1] = sb[1]; db[2] = sb[2]; db[3] = sb[3];
    }
    __syncthreads();
    #pragma unroll
    for (int ks = 0; ks < 2; ++ks) {
      int kk = ks * 32 + q * 8;
      bfx8 af[4];
      #pragma unroll
      for (int mi = 0; mi < 4; ++mi)
        af[mi] = *(const bfx8*)(a_s + (wm * 64 + mi * 16 + l15) * K2PAD + kk);
      #pragma unroll
      for (int ni = 0; ni < 4; ++ni) {
        bfx8 bv = *(const bfx8*)(b_s + (wn * 64 + ni * 16 + l15) * K2PAD + kk);
        #pragma unroll
        for (int mi = 0; mi < 4; ++mi)
          acc[mi][ni] = __builtin_amdgcn_mfma_f32_16x16x32_bf16(af[mi], bv, acc[mi][ni], 0, 0, 0);
      }
    }
    __syncthreads();
  }
  float* f0g = f0 + ((size_t)(g0 + gl) * NC0 + (size_t)mt * 128) * HD + (size_t)nt * 128;
  #pragma unroll
  for (int mi = 0; mi < 4; ++mi)
    #pragma unroll
    for (int ni = 0; ni < 4; ++ni) {
      int c = wm * 64 + mi * 16 + q * 4;
      int h = wn * 64 + ni * 16 + l15;
      #pragma unroll
      for (int r = 0; r < 4; ++r)
        atomicAdd(&f0g[(size_t)(c + r) * HD + h], acc[mi][ni][r]);
    }
}

// ---------------- K3: A1 = softmax(f0 @ W1 + b1), wave per row ----------------
__global__ __launch_bounds__(256) void k_assign1(
    const float* __restrict__ f0, const float* __restrict__ W1,
    const float* __restrict__ b1, float* __restrict__ A1) {
  int row = blockIdx.x * 4 + (threadIdx.x >> 6);
  int lane = threadIdx.x & 63;
  const float* fr = f0 + (size_t)row * 256;
  float acc = b1[lane];
  for (int k = 0; k < 256; k += 4) {
    float4 fv = *(const float4*)(fr + k);
    acc += fv.x * W1[(k    ) * 64 + lane];
    acc += fv.y * W1[(k + 1) * 64 + lane];
    acc += fv.z * W1[(k + 2) * 64 + lane];
    acc += fv.w * W1[(k + 3) * 64 + lane];
  }
  float m = acc;
  #pragma unroll
  for (int off = 1; off < 64; off <<= 1) m = fmaxf(m, __shfl_xor(m, off));
  float e = __expf(acc - m);
  float s = e;
  #pragma unroll
  for (int off = 1; off < 64; off <<= 1) s += __shfl_xor(s, off);
  A1[(size_t)row * 64 + lane] = e / s;
}

// ---------------- K4: f1[b][c*256+h] = sum_c0 A1[b][c0][c] * f0[b][c0][h] ----------------
__global__ __launch_bounds__(256) void k_pool1(
    const float* __restrict__ A1, const float* __restrict__ f0, float* __restrict__ f1) {
  int b = blockIdx.x >> 2, cg = blockIdx.x & 3;
  int h = threadIdx.x;
  const float* a1p = A1 + (size_t)b * NC0 * NC1 + cg * 16;
  const float* f0p = f0 + (size_t)b * NC0 * HD + h;
  float acc[16];
  #pragma unroll
  for (int j = 0; j < 16; ++j) acc[j] = 0.f;
  for (int c0 = 0; c0 < 256; ++c0) {
    float fv = f0p[(size_t)c0 * 256];
    #pragma unroll
    for (int j = 0; j < 16; ++j) acc[j] += a1p[c0 * 64 + j] * fv;
  }
  float* d = f1 + (size_t)b * 16384 + (size_t)(cg * 16) * 256 + h;
  #pragma unroll
  for (int j = 0; j < 16; ++j) d[(size_t)j * 256] = acc[j];
}

// ---------------- K5a: out_tmp[b][h] += f1[b][k0..k0+1024] . Wf[k0..][h] ----------------
__global__ __launch_bounds__(256) void k_final_partial(
    const float* __restrict__ f1, const float* __restrict__ Wf, float* __restrict__ ot) {
  int b = blockIdx.x >> 4, kidx = blockIdx.x & 15;
  int h = threadIdx.x;
  const float* fp = f1 + (size_t)b * 16384 + (size_t)kidx * 1024;
  const float* wp = Wf + (size_t)kidx * 1024 * 256 + h;
  float acc = 0.f;
  for (int k = 0; k < 1024; k += 4) {
    float4 fv = *(const float4*)(fp + k);
    acc += fv.x * wp[(size_t)(k    ) * 256];
    acc += fv.y * wp[(size_t)(k + 1) * 256];
    acc += fv.z * wp[(size_t)(k + 2) * 256];
    acc += fv.w * wp[(size_t)(k + 3) * 256];
  }
  atomicAdd(&ot[b * 256 + h], acc);
}

// ---------------- K5b: out = relu(out_tmp + bf) ----------------
__global__ __launch_bounds__(256) void k_final_out(
    const float* __restrict__ ot, const float* __restrict__ bfv, float* __restrict__ out) {
  int i = blockIdx.x * 256 + threadIdx.x;
  float v = ot[i] + bfv[i & 255];
  out[i] = v > 0.f ? v : 0.f;
}

extern "C" void kernel_launch(void* const* d_in, const int* in_sizes, int n_in,
                              void* d_out, int out_size, void* d_ws, size_t ws_size,
                              hipStream_t stream) {
  const float* x   = (const float*)d_in[0];
  const float* W0  = (const float*)d_in[3];
  const float* b0  = (const float*)d_in[4];
  const float* W1  = (const float*)d_in[5];
  const float* b1  = (const float*)d_in[6];
  const float* Wf  = (const float*)d_in[7];
  const float* bfv = (const float*)d_in[8];
  float* out = (float*)d_out;
  char* ws = (char*)d_ws;

  // workspace layout (fixed ~38 MB + 4 MB per chunked graph)
  float* f0 = (float*)(ws);                                   // 16 MB
  float* A1 = (float*)(ws + ((size_t)16 << 20));              // 4 MB
  float* f1 = (float*)(ws + ((size_t)20 << 20));              // 16 MB
  float* ot = (float*)(ws + ((size_t)36 << 20));              // 64 KB
  unsigned short* W0T = (unsigned short*)(ws + ((size_t)36 << 20) + 65536);  // 128 KB
  size_t chunk_off = ((size_t)36 << 20) + 65536 + 131072;
  size_t per_graph = (size_t)2 * NC0 * NPG * 2;               // xT_g + A0T_g = 4 MB
  size_t avail = ws_size > chunk_off ? ws_size - chunk_off : 0;
  int G = (int)(avail / per_graph);
  if (G > 64) G = 64;
  if (G < 1) G = 1;
  unsigned short* xT  = (unsigned short*)(ws + chunk_off);
  unsigned short* A0T = xT + (size_t)G * HD * NPG;

  hipMemsetAsync(f0, 0, (size_t)16 << 20, stream);
  hipMemsetAsync(ot, 0, 65536, stream);
  k_w0t<<<256, 256, 0, stream>>>(W0, W0T);

  int ksplit = 2;
  while (G * 4 * ksplit < 512 && ksplit < 16) ksplit <<= 1;

  for (int g0 = 0; g0 < NG; g0 += G) {
    int gc = (NG - g0 < G) ? (NG - g0) : G;
    k_xt<<<gc * 64, 256, 0, stream>>>(x, xT, g0);
    k_assign0<<<gc * 32, 512, 0, stream>>>(x, W0T, b0, A0T, g0);
    k_pool0<<<gc * 4 * ksplit, 256, 0, stream>>>(A0T, xT, f0, g0, NPG / ksplit, ksplit);
  }
  k_assign1<<<4096, 256, 0, stream>>>(f0, W1, b1, A1);
  k_pool1<<<256, 256, 0, stream>>>(A1, f0, f1);
  k_final_partial<<<64 * 16, 256, 0, stream>>>(f1, Wf, ot);
  k_final_out<<<64, 256, 0, stream>>>(ot, bfv, out);
}

// Round 2
// 750.689 us; speedup vs baseline: 1.1190x; 1.1190x over previous
//
#include <hip/hip_runtime.h>
#include <stdint.h>

#define NG   64
#define NPG  4096
#define HD   256
#define NC0  256
#define NC1  64
#define KSPLIT 2

typedef __attribute__((ext_vector_type(8))) short bfx8;   // 8 bf16 (4 VGPRs)
typedef __attribute__((ext_vector_type(4))) float fx4;    // MFMA acc

__device__ __forceinline__ unsigned short f2bf(float f) {
  union { float f; unsigned int u; } v; v.f = f;
  return (unsigned short)((v.u + 0x7FFFu + ((v.u >> 16) & 1u)) >> 16);  // RNE
}
__device__ __forceinline__ unsigned int pack2(float a, float b) {
  return (unsigned int)f2bf(a) | ((unsigned int)f2bf(b) << 16);
}

// async global->LDS, 16B per lane; LDS dest = wave-uniform base + lane*16
#define ASYNC_COPY16(gptr, lptr) \
  __builtin_amdgcn_global_load_lds((const __attribute__((address_space(1))) unsigned int*)(gptr), \
                                   (__attribute__((address_space(3))) unsigned int*)(lptr), 16, 0, 0)

// ---------------- W0 -> W0F: MFMA B-fragment order, bf16 ----------------
// granule gid: l15=c&15, q=(k>>3)&3, ks=(k>>5)&1, kc=k>>6, cblk=c>>4
// W0F[gid*8 + j] = bf16(W0[(kbase+j)*256 + c])
__global__ __launch_bounds__(256) void k_w0f(const float* __restrict__ W0,
                                             unsigned short* __restrict__ W0F) {
  int gid = blockIdx.x * 256 + threadIdx.x;   // 8192 granules
  int l15 = gid & 15;
  int q   = (gid >> 4) & 3;
  int ks  = (gid >> 6) & 1;
  int kc  = (gid >> 7) & 3;
  int cblk = gid >> 9;
  int c = cblk * 16 + l15;
  int kb = kc * 64 + ks * 32 + q * 8;
  unsigned int u[4];
  #pragma unroll
  for (int j = 0; j < 8; j += 2)
    u[j >> 1] = pack2(W0[(size_t)(kb + j) * 256 + c], W0[(size_t)(kb + j + 1) * 256 + c]);
  *(float4*)(W0F + (size_t)gid * 8) = *(float4*)u;
}

// ---------------- K1: softmax(x@W0+b0) -> A0T (bf16 [c][node]); also emits xT ----------------
// 512 thr (8 waves), tile 128 nodes x 256 clusters, K=256 (BK=64, dbuf LDS)
#define XSP 72
__global__ __launch_bounds__(512, 2) void k_assign0(
    const float* __restrict__ x, const unsigned short* __restrict__ W0F,
    const float* __restrict__ b0, unsigned short* __restrict__ A0T,
    unsigned short* __restrict__ xT, int g0) {
  __shared__ unsigned short xs[2][128 * XSP];   // 2 x 18432 B
  __shared__ float red[128 * 4];
  unsigned short* at = (unsigned short*)xs;     // epilogue alias [128 c][136 n] = 34816 B

  int gl = blockIdx.x >> 5, nt = blockIdx.x & 31;
  int tid = threadIdx.x;
  int wave = tid >> 6, lane = tid & 63;
  int wm = wave >> 2, wn = wave & 3;
  int l15 = lane & 15, q = lane >> 4;

  fx4 acc[4][4];
  #pragma unroll
  for (int i = 0; i < 4; ++i)
    #pragma unroll
    for (int j = 0; j < 4; ++j) acc[i][j] = fx4{0.f, 0.f, 0.f, 0.f};

  const float* xbase = x + ((size_t)(g0 + gl) * NPG + (size_t)nt * 128) * HD;
  int snode = tid >> 2, sseg = (tid & 3) * 16;   // 128 rows x 4 segs of 16 floats

  // stage chunk 0 into buf 0
  {
    const float4* src = (const float4*)(xbase + (size_t)snode * HD + sseg);
    float4 v0 = src[0], v1 = src[1], v2 = src[2], v3 = src[3];
    float4 pv[2]; unsigned int* pu = (unsigned int*)pv;
    pu[0] = pack2(v0.x, v0.y); pu[1] = pack2(v0.z, v0.w);
    pu[2] = pack2(v1.x, v1.y); pu[3] = pack2(v1.z, v1.w);
    pu[4] = pack2(v2.x, v2.y); pu[5] = pack2(v2.z, v2.w);
    pu[6] = pack2(v3.x, v3.y); pu[7] = pack2(v3.z, v3.w);
    float4* d = (float4*)&xs[0][snode * XSP + sseg];
    d[0] = pv[0]; d[1] = pv[1];
  }
  __syncthreads();

  for (int kc = 0; kc < 4; ++kc) {
    int buf = kc & 1;
    if (kc < 3) {   // stage kc+1 into other buffer (issue loads early)
      const float4* src = (const float4*)(xbase + (size_t)snode * HD + (kc + 1) * 64 + sseg);
      float4 v0 = src[0], v1 = src[1], v2 = src[2], v3 = src[3];
      float4 pv[2]; unsigned int* pu = (unsigned int*)pv;
      pu[0] = pack2(v0.x, v0.y); pu[1] = pack2(v0.z, v0.w);
      pu[2] = pack2(v1.x, v1.y); pu[3] = pack2(v1.z, v1.w);
      pu[4] = pack2(v2.x, v2.y); pu[5] = pack2(v2.z, v2.w);
      pu[6] = pack2(v3.x, v3.y); pu[7] = pack2(v3.z, v3.w);
      float4* d = (float4*)&xs[buf ^ 1][snode * XSP + sseg];
      d[0] = pv[0]; d[1] = pv[1];
    }
    // MFMA on buf; B fragments straight from L2-resident W0F
    #pragma unroll
    for (int ks = 0; ks < 2; ++ks) {
      int kk = ks * 32 + q * 8;
      bfx8 af[4];
      #pragma unroll
      for (int mi = 0; mi < 4; ++mi)
        af[mi] = *(const bfx8*)&xs[buf][(wm * 64 + mi * 16 + l15) * XSP + kk];
      #pragma unroll
      for (int ni = 0; ni < 4; ++ni) {
        bfx8 bv = *(const bfx8*)(W0F + ((size_t)(((wn * 4 + ni) * 8 + kc * 2 + ks) * 64 + lane)) * 8);
        #pragma unroll
        for (int mi = 0; mi < 4; ++mi)
          acc[mi][ni] = __builtin_amdgcn_mfma_f32_16x16x32_bf16(af[mi], bv, acc[mi][ni], 0, 0, 0);
      }
    }
    // emit xT[h][node] for this k-chunk from LDS (fused transpose)
    {
      int hl = tid >> 3;             // 0..63
      int seg = (tid & 7) * 16;      // node segment
      unsigned int u[8];
      #pragma unroll
      for (int i = 0; i < 16; i += 2) {
        unsigned short a = xs[buf][(seg + i) * XSP + hl];
        unsigned short b = xs[buf][(seg + i + 1) * XSP + hl];
        u[i >> 1] = (unsigned int)a | ((unsigned int)b << 16);
      }
      float4* dst = (float4*)(xT + ((size_t)gl * HD + kc * 64 + hl) * NPG + (size_t)nt * 128 + seg);
      dst[0] = *(float4*)&u[0];
      dst[1] = *(float4*)&u[4];
    }
    __syncthreads();
  }

  // ---- epilogue: bias + softmax over 256 clusters per node-row ----
  float bv4[4];
  #pragma unroll
  for (int ni = 0; ni < 4; ++ni) bv4[ni] = b0[wn * 64 + ni * 16 + l15];
  #pragma unroll
  for (int mi = 0; mi < 4; ++mi)
    #pragma unroll
    for (int ni = 0; ni < 4; ++ni)
      #pragma unroll
      for (int r = 0; r < 4; ++r) acc[mi][ni][r] += bv4[ni];

  float mrow[4][4];
  #pragma unroll
  for (int mi = 0; mi < 4; ++mi)
    #pragma unroll
    for (int r = 0; r < 4; ++r) {
      float m = fmaxf(fmaxf(acc[mi][0][r], acc[mi][1][r]), fmaxf(acc[mi][2][r], acc[mi][3][r]));
      #pragma unroll
      for (int off = 1; off < 16; off <<= 1) m = fmaxf(m, __shfl_xor(m, off));
      mrow[mi][r] = m;
    }
  if (l15 == 0) {
    #pragma unroll
    for (int mi = 0; mi < 4; ++mi)
      #pragma unroll
      for (int r = 0; r < 4; ++r)
        red[(wm * 64 + mi * 16 + q * 4 + r) * 4 + wn] = mrow[mi][r];
  }
  __syncthreads();
  #pragma unroll
  for (int mi = 0; mi < 4; ++mi)
    #pragma unroll
    for (int r = 0; r < 4; ++r) {
      float4 rv = *(const float4*)&red[(wm * 64 + mi * 16 + q * 4 + r) * 4];
      mrow[mi][r] = fmaxf(fmaxf(rv.x, rv.y), fmaxf(rv.z, rv.w));
    }
  __syncthreads();
  float srow[4][4];
  #pragma unroll
  for (int mi = 0; mi < 4; ++mi)
    #pragma unroll
    for (int r = 0; r < 4; ++r) {
      float s = 0.f;
      #pragma unroll
      for (int ni = 0; ni < 4; ++ni) {
        float e = __expf(acc[mi][ni][r] - mrow[mi][r]);
        acc[mi][ni][r] = e; s += e;
      }
      #pragma unroll
      for (int off = 1; off < 16; off <<= 1) s += __shfl_xor(s, off);
      srow[mi][r] = s;
    }
  if (l15 == 0) {
    #pragma unroll
    for (int mi = 0; mi < 4; ++mi)
      #pragma unroll
      for (int r = 0; r < 4; ++r)
        red[(wm * 64 + mi * 16 + q * 4 + r) * 4 + wn] = srow[mi][r];
  }
  __syncthreads();
  #pragma unroll
  for (int mi = 0; mi < 4; ++mi)
    #pragma unroll
    for (int r = 0; r < 4; ++r) {
      float4 rv = *(const float4*)&red[(wm * 64 + mi * 16 + q * 4 + r) * 4];
      float inv = 1.f / (rv.x + rv.y + rv.z + rv.w);
      #pragma unroll
      for (int ni = 0; ni < 4; ++ni) acc[mi][ni][r] *= inv;
    }
  __syncthreads();   // xs dead; reuse as 'at'

  // ---- transposed store: A0T[gl][c][node], two 128-cluster phases via LDS ----
  unsigned short* A0Tg = A0T + (size_t)gl * NC0 * NPG + (size_t)nt * 128;
  #pragma unroll
  for (int p = 0; p < 2; ++p) {
    if ((wn >> 1) == p) {
      int cb = (wn & 1) * 64;
      #pragma unroll
      for (int mi = 0; mi < 4; ++mi) {
        int ncol = wm * 64 + mi * 16 + q * 4;
        #pragma unroll
        for (int ni = 0; ni < 4; ++ni) {
          int cl = cb + ni * 16 + l15;
          uint2 w;
          w.x = pack2(acc[mi][ni][0], acc[mi][ni][1]);
          w.y = pack2(acc[mi][ni][2], acc[mi][ni][3]);
          *(uint2*)(at + cl * 136 + ncol) = w;
        }
      }
    }
    __syncthreads();
    {
      int row = tid >> 2, seg = (tid & 3) * 32;
      const float4* s4 = (const float4*)(at + row * 136 + seg);
      float4 a = s4[0], b = s4[1], c = s4[2], d = s4[3];
      float4* d4 = (float4*)(A0Tg + (size_t)(p * 128 + row) * NPG + seg);
      d4[0] = a; d4[1] = b; d4[2] = c; d4[3] = d;
    }
    __syncthreads();
  }
}

// ---------------- K2: f0p[kidx][g][c][h] = A0T[g][c][:] . xT[g][h][:] (no atomics) ----------------
// m97 structure: global_load_lds width-16 staging, XOR-swizzled 16B granules, 128x128 tile
__global__ __launch_bounds__(256, 2) void k_pool0(
    const unsigned short* __restrict__ A0T, const unsigned short* __restrict__ xT,
    float* __restrict__ f0p, int g0) {
  __shared__ unsigned short a_s[128 * 64];
  __shared__ unsigned short b_s[128 * 64];
  int bid = blockIdx.x;
  int kidx = bid & 1;
  int nt = (bid >> 1) & 1;
  int mt = (bid >> 2) & 1;
  int gl = bid >> 3;

  int tid = threadIdx.x;
  int wave = tid >> 6, lane = tid & 63;
  int wm = wave >> 1, wn = wave & 1;
  int l15 = lane & 15, q = lane >> 4;

  const int KPER = NPG / KSPLIT;   // 2048
  const unsigned short* abase = A0T + ((size_t)gl * NC0 + (size_t)mt * 128) * NPG + (size_t)kidx * KPER;
  const unsigned short* bbase = xT  + ((size_t)gl * HD  + (size_t)nt * 128) * NPG + (size_t)kidx * KPER;

  fx4 acc[4][4];
  #pragma unroll
  for (int i = 0; i < 4; ++i)
    #pragma unroll
    for (int j = 0; j < 4; ++j) acc[i][j] = fx4{0.f, 0.f, 0.f, 0.f};

  int srow = lane >> 3;                 // 0..7 row within 8-row group
  int sg   = (lane & 7) ^ srow;         // swizzled 16B granule
  size_t soff = (size_t)srow * NPG + (size_t)sg * 8;   // shorts

  for (int k0 = 0; k0 < KPER; k0 += 64) {
    #pragma unroll
    for (int i = 0; i < 4; ++i) {
      int r0 = wave * 32 + i * 8;
      ASYNC_COPY16(abase + (size_t)r0 * NPG + k0 + soff, &a_s[r0 * 64]);
      ASYNC_COPY16(bbase + (size_t)r0 * NPG + k0 + soff, &b_s[r0 * 64]);
    }
    __syncthreads();
    #pragma unroll
    for (int ks = 0; ks < 2; ++ks) {
      int gx = ((ks * 4 + q) ^ (l15 & 7)) << 3;   // swizzled granule offset (shorts)
      bfx8 af[4], bf[4];
      #pragma unroll
      for (int mi = 0; mi < 4; ++mi)
        af[mi] = *(const bfx8*)&a_s[(wm * 64 + mi * 16 + l15) * 64 + gx];
      #pragma unroll
      for (int ni = 0; ni < 4; ++ni)
        bf[ni] = *(const bfx8*)&b_s[(wn * 64 + ni * 16 + l15) * 64 + gx];
      #pragma unroll
      for (int ni = 0; ni < 4; ++ni)
        #pragma unroll
        for (int mi = 0; mi < 4; ++mi)
          acc[mi][ni] = __builtin_amdgcn_mfma_f32_16x16x32_bf16(af[mi], bf[ni], acc[mi][ni], 0, 0, 0);
    }
    __syncthreads();
  }

  float* dst = f0p + (size_t)kidx * NG * NC0 * HD
             + ((size_t)(g0 + gl) * NC0 + (size_t)mt * 128) * HD + (size_t)nt * 128;
  #pragma unroll
  for (int mi = 0; mi < 4; ++mi)
    #pragma unroll
    for (int ni = 0; ni < 4; ++ni) {
      int c = wm * 64 + mi * 16 + q * 4;
      int h = wn * 64 + ni * 16 + l15;
      #pragma unroll
      for (int r = 0; r < 4; ++r)
        dst[(size_t)(c + r) * HD + h] = acc[mi][ni][r];
    }
}

// ---------------- f0 = f0p0 + f0p1 (in place: f0 == f0p0) ----------------
__global__ __launch_bounds__(256) void k_f0sum(float* __restrict__ f0) {
  size_t i = ((size_t)blockIdx.x * 256 + threadIdx.x) * 4;
  float4 a = *(const float4*)(f0 + i);
  float4 b = *(const float4*)(f0 + (size_t)NG * NC0 * HD + i);
  a.x += b.x; a.y += b.y; a.z += b.z; a.w += b.w;
  *(float4*)(f0 + i) = a;
}

// ---------------- K3: A1 = softmax(f0 @ W1 + b1), wave per row ----------------
__global__ __launch_bounds__(256) void k_assign1(
    const float* __restrict__ f0, const float* __restrict__ W1,
    const float* __restrict__ b1, float* __restrict__ A1) {
  int row = blockIdx.x * 4 + (threadIdx.x >> 6);
  int lane = threadIdx.x & 63;
  const float* fr = f0 + (size_t)row * 256;
  float acc = b1[lane];
  for (int k = 0; k < 256; k += 4) {
    float4 fv = *(const float4*)(fr + k);
    acc += fv.x * W1[(k    ) * 64 + lane];
    acc += fv.y * W1[(k + 1) * 64 + lane];
    acc += fv.z * W1[(k + 2) * 64 + lane];
    acc += fv.w * W1[(k + 3) * 64 + lane];
  }
  float m = acc;
  #pragma unroll
  for (int off = 1; off < 64; off <<= 1) m = fmaxf(m, __shfl_xor(m, off));
  float e = __expf(acc - m);
  float s = e;
  #pragma unroll
  for (int off = 1; off < 64; off <<= 1) s += __shfl_xor(s, off);
  A1[(size_t)row * 64 + lane] = e / s;
}

// ---------------- K4: f1[b][c*256+h] = sum_c0 A1[b][c0][c] * f0[b][c0][h] ----------------
__global__ __launch_bounds__(256) void k_pool1(
    const float* __restrict__ A1, const float* __restrict__ f0, float* __restrict__ f1) {
  int b = blockIdx.x >> 2, cg = blockIdx.x & 3;
  int h = threadIdx.x;
  const float* a1p = A1 + (size_t)b * NC0 * NC1 + cg * 16;
  const float* f0p = f0 + (size_t)b * NC0 * HD + h;
  float acc[16];
  #pragma unroll
  for (int j = 0; j < 16; ++j) acc[j] = 0.f;
  for (int c0 = 0; c0 < 256; ++c0) {
    float fv = f0p[(size_t)c0 * 256];
    #pragma unroll
    for (int j = 0; j < 16; ++j) acc[j] += a1p[c0 * 64 + j] * fv;
  }
  float* d = f1 + (size_t)b * 16384 + (size_t)(cg * 16) * 256 + h;
  #pragma unroll
  for (int j = 0; j < 16; ++j) d[(size_t)j * 256] = acc[j];
}

// ---------------- K5a: ot[b][h] += f1[b][k0..+1024] . Wf[k0..][h] ----------------
__global__ __launch_bounds__(256) void k_final_partial(
    const float* __restrict__ f1, const float* __restrict__ Wf, float* __restrict__ ot) {
  int b = blockIdx.x >> 4, kidx = blockIdx.x & 15;
  int h = threadIdx.x;
  const float* fp = f1 + (size_t)b * 16384 + (size_t)kidx * 1024;
  const float* wp = Wf + (size_t)kidx * 1024 * 256 + h;
  float acc = 0.f;
  for (int k = 0; k < 1024; k += 4) {
    float4 fv = *(const float4*)(fp + k);
    acc += fv.x * wp[(size_t)(k    ) * 256];
    acc += fv.y * wp[(size_t)(k + 1) * 256];
    acc += fv.z * wp[(size_t)(k + 2) * 256];
    acc += fv.w * wp[(size_t)(k + 3) * 256];
  }
  atomicAdd(&ot[b * 256 + h], acc);
}

// ---------------- K5b: out = relu(ot + bf) ----------------
__global__ __launch_bounds__(256) void k_final_out(
    const float* __restrict__ ot, const float* __restrict__ bfv, float* __restrict__ out) {
  int i = blockIdx.x * 256 + threadIdx.x;
  float v = ot[i] + bfv[i & 255];
  out[i] = v > 0.f ? v : 0.f;
}

extern "C" void kernel_launch(void* const* d_in, const int* in_sizes, int n_in,
                              void* d_out, int out_size, void* d_ws, size_t ws_size,
                              hipStream_t stream) {
  const float* x   = (const float*)d_in[0];
  const float* W0  = (const float*)d_in[3];
  const float* b0  = (const float*)d_in[4];
  const float* W1  = (const float*)d_in[5];
  const float* b1  = (const float*)d_in[6];
  const float* Wf  = (const float*)d_in[7];
  const float* bfv = (const float*)d_in[8];
  float* out = (float*)d_out;
  char* ws = (char*)d_ws;

  // layout: f0p [2x16 MB) @0 (partial0 doubles as final f0); ot @32M; W0F @32M+64K;
  // chunk region @32M+192K: xT (G*2MB) + A0T (G*2MB). f1 aliases xT, A1 aliases A0T.
  float* f0p = (float*)ws;
  float* f0  = f0p;
  float* ot  = (float*)(ws + ((size_t)32 << 20));
  unsigned short* W0F = (unsigned short*)(ws + ((size_t)32 << 20) + 65536);
  size_t chunk_off = ((size_t)32 << 20) + 65536 + 131072;
  size_t per_graph = (size_t)4 * HD * NPG;   // xT(2MB)+A0T(2MB)
  size_t avail = ws_size > chunk_off ? ws_size - chunk_off : 0;
  int G = (int)(avail / per_graph);
  if (G > 64) G = 64;
  if (G < 1) G = 1;
  unsigned short* xT  = (unsigned short*)(ws + chunk_off);
  unsigned short* A0T = xT + (size_t)G * HD * NPG;
  float* f1 = (float*)xT;    // 16 MB, used after k_pool0 (needs G>=8; ws floor gives G=64)
  float* A1 = (float*)A0T;   // 4 MB, used after k_pool0

  hipMemsetAsync(ot, 0, 65536, stream);
  k_w0f<<<32, 256, 0, stream>>>(W0, W0F);

  for (int g0 = 0; g0 < NG; g0 += G) {
    int gc = (NG - g0 < G) ? (NG - g0) : G;
    k_assign0<<<gc * 32, 512, 0, stream>>>(x, W0F, b0, A0T, xT, g0);
    k_pool0<<<gc * 4 * KSPLIT, 256, 0, stream>>>(A0T, xT, f0p, g0);
  }
  k_f0sum<<<4096, 256, 0, stream>>>(f0);
  k_assign1<<<4096, 256, 0, stream>>>(f0, W1, b1, A1);
  k_pool1<<<256, 256, 0, stream>>>(A1, f0, f1);
  k_final_partial<<<64 * 16, 256, 0, stream>>>(f1, Wf, ot);
  k_final_out<<<64, 256, 0, stream>>>(ot, bfv, out);
}